// Round 9
// baseline (227.307 us; speedup 1.0000x reference)
//
#include <hip/hip_runtime.h>
#include <math.h>

#define NN 50000
#define NE 800000
#define DD 128
#define HU 256
#define SLOPE 0.2f
#define EPSV 1e-7f
#define SCAN_B 1024
#define NBLK ((NN + SCAN_B - 1) / SCAN_B)   // 49

typedef __attribute__((ext_vector_type(8))) short short8;
typedef __attribute__((ext_vector_type(4))) float f32x4;

__device__ __forceinline__ float bf2f(unsigned short u) {
  union { unsigned int i; float f; } v; v.i = ((unsigned int)u) << 16; return v.f;
}
__device__ __forceinline__ unsigned short f2bf(float f) {
  union { float ff; unsigned int i; } v; v.ff = f;
  unsigned int r = v.i + 0x7FFFu + ((v.i >> 16) & 1u);   // RNE
  return (unsigned short)(r >> 16);
}
__device__ __forceinline__ float bflo(unsigned int u) {
  union { unsigned int i; float f; } v; v.i = u << 16; return v.f;
}
__device__ __forceinline__ float bfhi(unsigned int u) {
  union { unsigned int i; float f; } v; v.i = u & 0xFFFF0000u; return v.f;
}
template <int CTRL>
__device__ __forceinline__ float qadd(float p) {
  int pi = __builtin_bit_cast(int, p);
  int q = __builtin_amdgcn_update_dpp(pi, pi, CTRL, 0xF, 0xF, false);
  return p + __builtin_bit_cast(float, q);
}
#define DPP_XOR1 0xB1   // quad_perm [1,0,3,2]
#define DPP_XOR2 0x4E   // quad_perm [2,3,0,1]

// ---------------------------------------------------------------------------
// prep: kernbT[col][k] = bf16(kern[k][col]); also zeros cnt (folds memset).
// ---------------------------------------------------------------------------
__global__ __launch_bounds__(256) void prep_kernel(
    const float* __restrict__ kern, unsigned short* __restrict__ kernbT,
    int* __restrict__ cnt)
{
  int i = blockIdx.x * 256 + threadIdx.x;   // 32768 threads
  if (i < DD * HU) {
    int col = i & 255, k = i >> 8;
    kernbT[(size_t)col * DD + k] = f2bf(kern[(size_t)k * HU + col]);
  }
  for (int c = i; c < NN; c += 128 * 256) cnt[c] = 0;
}

// ---------------------------------------------------------------------------
// xp = bf16(x) @ bf16(kernel) via MFMA 16x16x32_bf16; output bf16.
// (unchanged — verified, absmax 0.0078)
// ---------------------------------------------------------------------------
__global__ __launch_bounds__(256) void gemm_mfma_kernel(
    const float* __restrict__ x, const unsigned short* __restrict__ kernbT,
    unsigned short* __restrict__ xpb)
{
  __shared__ __align__(16) unsigned char ldsA[64 * 256];    // 16 KB
  __shared__ __align__(16) unsigned char ldsB[128 * 256];   // 32 KB (one half)
  const int tid = threadIdx.x;
  const int r0 = blockIdx.x * 64;

#pragma unroll
  for (int c = 0; c < 4; ++c) {
    int cc = tid + 256 * c;
    int row = cc >> 4;
    int kp  = (cc & 15) * 8;
    float4 va = make_float4(0.f,0.f,0.f,0.f), vb = va;
    if (r0 + row < NN) {
      const float* g = x + (size_t)(r0 + row) * DD + kp;
      va = *(const float4*)g; vb = *(const float4*)(g + 4);
    }
    uint4 u;
    u.x = (unsigned)f2bf(va.x) | ((unsigned)f2bf(va.y) << 16);
    u.y = (unsigned)f2bf(va.z) | ((unsigned)f2bf(va.w) << 16);
    u.z = (unsigned)f2bf(vb.x) | ((unsigned)f2bf(vb.y) << 16);
    u.w = (unsigned)f2bf(vb.z) | ((unsigned)f2bf(vb.w) << 16);
    *(uint4*)(ldsA + row * 256 + ((kp * 2) ^ ((row & 7) << 4))) = u;
  }
  __syncthreads();

  const int lane = tid & 63, wv = tid >> 6;
  const int arow = wv * 16 + (lane & 15);
  const int kb = (lane >> 4) * 16;
  short8 af[4];
#pragma unroll
  for (int ks = 0; ks < 4; ++ks) {
    int kbyte = ks * 64 + kb;
    af[ks] = *(const short8*)(ldsA + arow * 256 + (kbyte ^ ((arow & 7) << 4)));
  }

  f32x4 acc[16];
#pragma unroll
  for (int i = 0; i < 16; ++i) acc[i] = (f32x4){0.f, 0.f, 0.f, 0.f};

#pragma unroll
  for (int hb = 0; hb < 2; ++hb) {
    __syncthreads();
#pragma unroll
    for (int c = 0; c < 8; ++c) {
      int cc = tid + 256 * c;
      int col = cc >> 4;
      int kp  = (cc & 15) * 8;
      uint4 u = *(const uint4*)(kernbT + (size_t)(hb * 128 + col) * DD + kp);
      *(uint4*)(ldsB + col * 256 + ((kp * 2) ^ ((col & 7) << 4))) = u;
    }
    __syncthreads();
#pragma unroll
    for (int ks = 0; ks < 4; ++ks) {
      int kbyte = ks * 64 + kb;
#pragma unroll
      for (int n = 0; n < 8; ++n) {
        int colL = n * 16 + (lane & 15);
        short8 bf = *(const short8*)(ldsB + colL * 256 + (kbyte ^ ((colL & 7) << 4)));
        acc[hb * 8 + n] = __builtin_amdgcn_mfma_f32_16x16x32_bf16(
            af[ks], bf, acc[hb * 8 + n], 0, 0, 0);
      }
    }
  }

#pragma unroll
  for (int n16 = 0; n16 < 16; ++n16) {
    int col = n16 * 16 + (lane & 15);
#pragma unroll
    for (int r = 0; r < 4; ++r) {
      int row = r0 + wv * 16 + (lane >> 4) * 4 + r;
      if (row < NN) xpb[(size_t)row * HU + col] = f2bf(acc[n16][r]);
    }
  }
}

// ---------------------------------------------------------------------------
// hist: 2 edges/thread (int4 load); rank via atomic return.
// ---------------------------------------------------------------------------
__global__ __launch_bounds__(256) void hist_kernel(
    const int* __restrict__ edges, int* __restrict__ cnt, int* __restrict__ posw)
{
  int e2 = (blockIdx.x * 256 + threadIdx.x) * 2;
  if (e2 + 1 < NE) {
    int4 ed = *(const int4*)(edges + 2 * e2);   // (s0,t0,s1,t1)
    posw[e2]     = atomicAdd(&cnt[ed.y], 1);
    posw[e2 + 1] = atomicAdd(&cnt[ed.w], 1);
  } else if (e2 < NE) {
    int2 ed = ((const int2*)edges)[e2];
    posw[e2] = atomicAdd(&cnt[ed.y], 1);
  }
}

__global__ __launch_bounds__(1024) void scan1_kernel(
    const int* __restrict__ cnt, int* __restrict__ excl, int* __restrict__ btot)
{
  __shared__ int ws[16];
  const int tid = threadIdx.x, lane = tid & 63, wid = tid >> 6;
  const int i = blockIdx.x * SCAN_B + tid;
  int v = (i < NN) ? cnt[i] : 0;
  int sum = v;
#pragma unroll
  for (int off = 1; off < 64; off <<= 1) {
    int n = __shfl_up(sum, off, 64);
    if (lane >= off) sum += n;
  }
  if (lane == 63) ws[wid] = sum;
  __syncthreads();
  int wpre = 0;
  for (int w = 0; w < wid; ++w) wpre += ws[w];
  if (i < NN) excl[i] = wpre + sum - v;
  if (tid == SCAN_B - 1) btot[blockIdx.x] = wpre + sum;
}

__global__ __launch_bounds__(1024) void scan3_kernel(
    const int* __restrict__ excl, const int* __restrict__ btot,
    int* __restrict__ rowptr)
{
  __shared__ int s_off;
  const int tid = threadIdx.x;
  if (tid < 64) {
    int v = (tid < NBLK && tid < (int)blockIdx.x) ? btot[tid] : 0;
#pragma unroll
    for (int o = 32; o; o >>= 1) v += __shfl_xor(v, o, 64);
    if (tid == 0) s_off = v;
    if (blockIdx.x == NBLK - 1) {
      int g = (tid < NBLK) ? btot[tid] : 0;
#pragma unroll
      for (int o = 32; o; o >>= 1) g += __shfl_xor(g, o, 64);
      if (tid == 0) rowptr[NN] = g;
    }
  }
  __syncthreads();
  const int i = blockIdx.x * SCAN_B + tid;
  if (i < NN) rowptr[i] = excl[i] + s_off;
}

// ---------------------------------------------------------------------------
// scatter: atomic-free, 2 edges/thread.
// ---------------------------------------------------------------------------
__global__ __launch_bounds__(256) void scatter_kernel(
    const int* __restrict__ edges, const int* __restrict__ rowptr,
    const int* __restrict__ posw, int* __restrict__ srcidx)
{
  int e2 = (blockIdx.x * 256 + threadIdx.x) * 2;
  if (e2 + 1 < NE) {
    int4 ed = *(const int4*)(edges + 2 * e2);
    int2 pw = *(const int2*)(posw + e2);
    srcidx[rowptr[ed.y] + pw.x] = ed.x;
    srcidx[rowptr[ed.w] + pw.y] = ed.z;
  } else if (e2 < NE) {
    int2 ed = ((const int2*)edges)[e2];
    srcidx[rowptr[ed.y] + posw[e2]] = ed.x;
  }
}

// ---------------------------------------------------------------------------
// Fused aggregation, half-wave-per-edge, 4-deep prefetch ring, wave-uniform
// srcidx loads (pair indices loaded at uniform addresses -> SMEM path,
// selected per half by lane id; off the dependent VMEM chain).
// Tail masking: clamped index + w=0 (no OOB, no divergence).
// ---------------------------------------------------------------------------
__global__ __launch_bounds__(256) void aggregate_kernel(
    const unsigned short* __restrict__ xpb, const int* __restrict__ rowptr,
    const int* __restrict__ srcidx, const float* __restrict__ b_att,
    const float* __restrict__ k_att, const float* __restrict__ bias,
    float* __restrict__ out)
{
  const int t = blockIdx.x * 4 + (threadIdx.x >> 6);
  if (t >= NN) return;
  const int l = threadIdx.x & 63;
  const int half = l >> 5;       // 0: even edge of pair, 1: odd edge
  const int hl = l & 31;
  const int hu = hl * 8;         // 8 channels per lane

  const uint4 xtu = *(const uint4*)(xpb + (size_t)t * HU + hu);
  const float4 ka0 = *(const float4*)(k_att + hu);
  const float4 ka1 = *(const float4*)(k_att + hu + 4);
  const float4 ba0 = *(const float4*)(b_att + hu);
  const float4 ba1 = *(const float4*)(b_att + hu + 4);
  float xtb[8], ka[8];
  xtb[0] = bflo(xtu.x) + 2.f * ba0.x;  xtb[1] = bfhi(xtu.x) + 2.f * ba0.y;
  xtb[2] = bflo(xtu.y) + 2.f * ba0.z;  xtb[3] = bfhi(xtu.y) + 2.f * ba0.w;
  xtb[4] = bflo(xtu.z) + 2.f * ba1.x;  xtb[5] = bfhi(xtu.z) + 2.f * ba1.y;
  xtb[6] = bflo(xtu.w) + 2.f * ba1.z;  xtb[7] = bfhi(xtu.w) + 2.f * ba1.w;
  ka[0] = ka0.x; ka[1] = ka0.y; ka[2] = ka0.z; ka[3] = ka0.w;
  ka[4] = ka1.x; ka[5] = ka1.y; ka[6] = ka1.z; ka[7] = ka1.w;

  const int beg = rowptr[t], end = rowptr[t + 1];
  float sigma = 0.f;
  float acc[8];
#pragma unroll
  for (int c = 0; c < 8; ++c) acc[c] = 0.f;

  if (beg < end) {
    const int npairs = (end - beg + 1) >> 1;
    const unsigned short* __restrict__ xph = xpb + hu;

    // uniform pair-index fetch, per-half select, clamped to end-1
    auto ldrow = [&](int i) -> uint4 {
      int jj = beg + 2 * i;                       // wave-uniform
      int s0 = srcidx[min(jj, end - 1)];          // uniform addr
      int s1 = srcidx[min(jj + 1, end - 1)];      // uniform addr
      int s = half ? s1 : s0;
      return *(const uint4*)(xph + (size_t)s * HU);
    };

    uint4 q0 = ldrow(0);
    uint4 q1 = (npairs > 1) ? ldrow(1) : q0;
    uint4 q2 = (npairs > 2) ? ldrow(2) : q0;
    uint4 q3 = (npairs > 3) ? ldrow(3) : q0;

    for (int i = 0; i < npairs; ++i) {
      const uint4 cu = q0;
      q0 = q1; q1 = q2; q2 = q3;
      if (i + 4 < npairs) q3 = ldrow(i + 4);

      float xs[8];
      xs[0] = bflo(cu.x); xs[1] = bfhi(cu.x);
      xs[2] = bflo(cu.y); xs[3] = bfhi(cu.y);
      xs[4] = bflo(cu.z); xs[5] = bfhi(cu.z);
      xs[6] = bflo(cu.w); xs[7] = bfhi(cu.w);

      float p = 0.f;
#pragma unroll
      for (int c = 0; c < 8; ++c) {
        float f = xtb[c] + xs[c];
        f = fmaxf(f, SLOPE * f);
        p = fmaf(f, ka[c], p);
      }
      p = qadd<DPP_XOR1>(p);   // + lane^1
      p = qadd<DPP_XOR2>(p);   // + lane^2 -> full per-head score

      const bool valid = (beg + 2 * i + half) < end;
      const float w = valid ? __expf(p) : 0.f;
      sigma += w;
#pragma unroll
      for (int c = 0; c < 8; ++c) acc[c] = fmaf(w, xs[c], acc[c]);
    }
  }

  // merge the two halves (even/odd edge partials)
#pragma unroll
  for (int c = 0; c < 8; ++c) acc[c] += __shfl_xor(acc[c], 32, 64);
  sigma += __shfl_xor(sigma, 32, 64);

  if (half == 0) {
    const float inv = 1.f / (sigma + EPSV);
    const float4 bs0 = *(const float4*)(bias + hu);
    const float4 bs1 = *(const float4*)(bias + hu + 4);
    const float bsa[8] = {bs0.x, bs0.y, bs0.z, bs0.w, bs1.x, bs1.y, bs1.z, bs1.w};
    float o[8];
#pragma unroll
    for (int c = 0; c < 8; ++c) {
      float v = fmaf(acc[c], inv, bsa[c]);
      o[c] = (v > 0.f) ? v : (__expf(v) - 1.f);
    }
    *(float4*)(out + (size_t)t * HU + hu)     = make_float4(o[0], o[1], o[2], o[3]);
    *(float4*)(out + (size_t)t * HU + hu + 4) = make_float4(o[4], o[5], o[6], o[7]);
  }
}

extern "C" void kernel_launch(void* const* d_in, const int* in_sizes, int n_in,
                              void* d_out, int out_size, void* d_ws, size_t ws_size,
                              hipStream_t stream)
{
  const float* x     = (const float*)d_in[0];
  const int*   edges = (const int*)d_in[1];
  const float* kern  = (const float*)d_in[2];
  const float* katt  = (const float*)d_in[3];
  const float* batt  = (const float*)d_in[4];
  const float* bias  = (const float*)d_in[5];
  float* out = (float*)d_out;

  char* ws = (char*)d_ws;
  size_t off = 0;
  auto alignup = [](size_t v) { return (v + 255) & ~(size_t)255; };
  unsigned short* xpb = (unsigned short*)(ws + off); off = alignup(off + (size_t)NN * HU * sizeof(unsigned short)); // 25.6 MB
  int* cnt    = (int*)(ws + off); off = alignup(off + (size_t)NN * sizeof(int));
  int* rowptr = (int*)(ws + off); off = alignup(off + ((size_t)NN + 8) * sizeof(int));
  int* srcidx = (int*)(ws + off); off = alignup(off + (size_t)NE * sizeof(int));
  int* excl   = (int*)(ws + off); off = alignup(off + (size_t)NN * sizeof(int));
  int* btot   = (int*)(ws + off); off = alignup(off + 64 * sizeof(int));
  int* posw   = (int*)(ws + off); off = alignup(off + (size_t)NE * sizeof(int));
  unsigned short* kernbT = (unsigned short*)(ws + off); off = alignup(off + (size_t)DD * HU * sizeof(unsigned short));

  prep_kernel<<<128, 256, 0, stream>>>(kern, kernbT, cnt);
  gemm_mfma_kernel<<<(NN + 63) / 64, 256, 0, stream>>>(x, kernbT, xpb);
  hist_kernel<<<(NE / 2 + 255) / 256, 256, 0, stream>>>(edges, cnt, posw);
  scan1_kernel<<<NBLK, SCAN_B, 0, stream>>>(cnt, excl, btot);
  scan3_kernel<<<NBLK, SCAN_B, 0, stream>>>(excl, btot, rowptr);
  scatter_kernel<<<(NE / 2 + 255) / 256, 256, 0, stream>>>(edges, rowptr, posw, srcidx);
  aggregate_kernel<<<(NN + 3) / 4, 256, 0, stream>>>(xpb, rowptr, srcidx, batt, katt, bias, out);
}